// Round 6
// baseline (279.835 us; speedup 1.0000x reference)
//
#include <hip/hip_runtime.h>
#include <hip/hip_bf16.h>

// KAN Jacobi layer as bf16 MFMA GEMM (32x32x16), occupancy-tuned:
//   y[b,o,s] = bias[o] + sum_{k'=(d-1)*64+i, d=1..4} C2[o,k'] * P_d(tanh(x[b,i,s]))
//   bias[o]  = sum_i coeffs[i][o][0]   (P0 == 1)
// B=4, I=64, S=65536, O=128, K'=256. HBM floor ~31us (192 MiB @ 6.3 TB/s).
//
// Round-4/5/6: 512-thread blocks (8 waves), same 64 KB LDS table ->
// 2 blocks/CU = 16 waves/CU = 4 waves/SIMD (2x round-3 TLP; kernel was
// latency-bound: all pipes <15% utilized). Wave = (s-strip, o-half):
// acc = 2 x f32x16 (64 o x 32 s), A-frags 32 ds_read_b128/tile, tanh
// recomputed per o-half (VALU ~6%, cheap). <=128 VGPR via launch_bounds.

#define II 64
#define SS 65536
#define OO 128

typedef __attribute__((ext_vector_type(8))) short short8;
typedef __attribute__((ext_vector_type(4))) float f32x4;
typedef __attribute__((ext_vector_type(16))) float f32x16;

// ---------------- kernel 1a: coeffs -> swizzled bf16 table ----------------
__global__ __launch_bounds__(256)
void kan_prep_coeffs(const float* __restrict__ coeffs, ushort* __restrict__ cws) {
    int n = blockIdx.x * 256 + threadIdx.x;      // 40960 = 64*128*5 exactly
    int i = n / 640;
    int rem = n - i * 640;
    int o = rem / 5;
    int d = rem - o * 5;
    if (d == 0) return;                           // degree 0 -> bias kernel
    int kp = (d - 1) * 64 + i;                    // k' in [0,256)
    int byte = (o * 512 + kp * 2) ^ ((o & 7) << 4);
    __hip_bfloat16 h = __float2bfloat16(coeffs[n]);
    cws[byte >> 1] = *reinterpret_cast<ushort*>(&h);
}

// ---------------- kernel 1b: bias[o] = sum_i coeffs[i][o][0] ----------------
__global__ __launch_bounds__(128)
void kan_prep_bias(const float* __restrict__ coeffs, float* __restrict__ bias) {
    int o = threadIdx.x;
    float s = 0.f;
    #pragma unroll
    for (int i = 0; i < 64; ++i) s += coeffs[i * 640 + o * 5];
    bias[o] = s;
}

// ---------------- main MFMA kernel ----------------
__device__ __forceinline__ float fast_tanh(float v) {
    float e = exp2f(v * 2.885390082f);
    float r = __builtin_amdgcn_rcpf(e + 1.0f);
    return fmaf(-2.0f, r, 1.0f);
}

__device__ __forceinline__ short8 pack8(const float* p) {
    union { short8 v; uint u[4]; } r;
    #pragma unroll
    for (int q = 0; q < 4; ++q) {
        __hip_bfloat162 h = __float22bfloat162_rn(make_float2(p[2*q], p[2*q+1]));
        r.u[q] = *reinterpret_cast<uint*>(&h);
    }
    return r.v;
}

__global__ __launch_bounds__(512, 4)
void kan_mfma(const float* __restrict__ x, const ushort* __restrict__ cws,
              const float* __restrict__ bias, float* __restrict__ y) {
    __shared__ __align__(16) ushort clds[32768];   // 64 KB swizzled C2 table

    const int tid  = threadIdx.x;
    const int w    = tid >> 6;        // wave 0..7
    const int ws   = w & 3;           // s-strip within step
    const int wo   = w >> 2;          // o-half (0: o 0-63, 1: o 64-127)
    const int l    = tid & 63;
    const int lh   = l >> 5;          // k-half (0: k 0-7, 1: k 8-15)
    const int ls   = l & 31;          // s-column / o-row within tile
    const int b    = blockIdx.y;
    const int sgrp = blockIdx.x;      // 0..127 -> 512 samples per block

    // ---- stage C table: 64 KB = 8 iters x 512 thr x 16 B (linear) ----
    const char* gsrc  = (const char*)cws;
    char*       lbase = (char*)clds;
    #pragma unroll
    for (int q = 0; q < 8; ++q) {
        int off = (q * 512 + tid) * 16;
        __builtin_amdgcn_global_load_lds(
            (const __attribute__((address_space(1))) uint*)(gsrc + off),
            (__attribute__((address_space(3))) uint*)(lbase + off),
            16, 0, 0);
    }
    __syncthreads();

    const float* xb  = x + (size_t)b * II * SS;
    const int    swz = (ls & 7) << 4;
    const int    ob  = wo * 64;       // wave o-base

    #pragma unroll
    for (int st = 0; st < 4; ++st) {
        const int s0 = sgrp * 512 + st * 128 + ws * 32;

        // ---- load this tile's x: 32 loads, each 128 B contiguous/row ----
        float xbuf[4][8];
        #pragma unroll
        for (int ig = 0; ig < 4; ++ig) {
            const float* xp = xb + (size_t)(ig * 16 + 8 * lh) * SS + s0 + ls;
            #pragma unroll
            for (int j = 0; j < 8; ++j) xbuf[ig][j] = xp[(size_t)j * SS];
        }

        // ---- acc init = bias fragments (L1-hot after first tile) ----
        f32x16 acc[2];
        #pragma unroll
        for (int ot = 0; ot < 2; ++ot) {
            #pragma unroll
            for (int q = 0; q < 4; ++q) {
                f32x4 bv = *(const f32x4*)(bias + ob + ot * 32 + q * 8 + 4 * lh);
                #pragma unroll
                for (int r = 0; r < 4; ++r) acc[ot][q * 4 + r] = bv[r];
            }
        }

        // ---- per i-group: tanh + Jacobi + pack, then 8 MFMA ----
        #pragma unroll
        for (int ig = 0; ig < 4; ++ig) {
            float p1a[8], p2a[8], p3a[8], p4a[8];
            #pragma unroll
            for (int j = 0; j < 8; ++j) {
                float t  = fast_tanh(xbuf[ig][j]);
                float p1 = t + t;                                   // P1 = 2x
                float p2 = fmaf(1.875f * t, p1, -0.75f);            // P2
                float p3 = fmaf(1.8666666666666667f * t, p2, -0.8f * p1);
                float p4 = fmaf(1.875f * t, p3, -0.8333333333333333f * p2);
                p1a[j] = p1; p2a[j] = p2; p3a[j] = p3; p4a[j] = p4;
            }
            short8 bf[4];
            bf[0] = pack8(p1a); bf[1] = pack8(p2a);
            bf[2] = pack8(p3a); bf[3] = pack8(p4a);

            #pragma unroll
            for (int di = 0; di < 4; ++di) {
                const int kt = di * 4 + ig;               // k-window
                #pragma unroll
                for (int ot = 0; ot < 2; ++ot) {
                    const int o    = ob + ot * 32 + ls;
                    const int boff = (o * 512 + kt * 32 + 16 * lh) ^ swz;
                    short8 a = *(const short8*)(lbase + boff);
                    acc[ot] = __builtin_amdgcn_mfma_f32_32x32x16_bf16(a, bf[di], acc[ot], 0, 0, 0);
                }
            }
        }

        // ---- store: D col = l&31 (s), row = (r&3)+8*(r>>2)+4*(l>>5) (o) ----
        // per store instr: 2 x 32 lanes x 4 B = 2 full 128 B lines
        #pragma unroll
        for (int ot = 0; ot < 2; ++ot) {
            #pragma unroll
            for (int q = 0; q < 4; ++q) {
                #pragma unroll
                for (int rr = 0; rr < 4; ++rr) {
                    const int orow = ob + ot * 32 + rr + 8 * q + 4 * lh;
                    y[(size_t)(b * OO + orow) * SS + s0 + ls] = acc[ot][q * 4 + rr];
                }
            }
        }
    }
}

extern "C" void kernel_launch(void* const* d_in, const int* in_sizes, int n_in,
                              void* d_out, int out_size, void* d_ws, size_t ws_size,
                              hipStream_t stream) {
    const float* x      = (const float*)d_in[0];
    const float* coeffs = (const float*)d_in[1];
    float* y            = (float*)d_out;

    ushort* cws  = (ushort*)d_ws;                        // 64 KB bf16 table
    float*  bias = (float*)((char*)d_ws + 65536);        // 512 B

    kan_prep_coeffs<<<dim3(160), dim3(256), 0, stream>>>(coeffs, cws);
    kan_prep_bias  <<<dim3(1),   dim3(128), 0, stream>>>(coeffs, bias);
    kan_mfma       <<<dim3(128, 4), dim3(512), 0, stream>>>(x, cws, bias, y);
}

// Round 11
// 193.535 us; speedup vs baseline: 1.4459x; 1.4459x over previous
//
#include <hip/hip_runtime.h>
#include <hip/hip_bf16.h>

// KAN Jacobi layer as bf16 MFMA GEMM (32x32x16), write-granule-tuned v2:
//   y[b,o,s] = bias[o] + sum_{k'=(d-1)*64+i, d=1..4} C2[o,k'] * P_d(tanh(x[b,i,s]))
//   bias[o]  = sum_i coeffs[i][o][0]   (P0 == 1)
// B=4, I=64, S=65536, O=128, K'=256. HBM floor ~31us (192 MiB @ 6.3 TB/s).
//
// Round-11: round-7's permlane epilogue FAILED validation (absmax 4.6 --
// inline-asm swap suspect). Replaced by EVEN/ODD s-interleaved tile pairs:
// tile A col c <-> s0+2c, tile B col c <-> s0+2c+1. Every acc reg pair
// (accA,accB) = two consecutive s of one y row -> float2 store (dwordx2):
// each 32-lane half writes 256 B contiguous. x loads are float2 as well
// (lane gets even+odd sample in one 8B load, 256 B fully-consumed segments).
// No cross-lane ops; math identical to passing rounds 2/3/6 up to an
// s-column permutation applied consistently to B-frags and stores.
// A-frags shared across the pair (halves LDS reads).

#define II 64
#define SS 65536
#define OO 128

typedef __attribute__((ext_vector_type(8))) short short8;
typedef __attribute__((ext_vector_type(4))) float f32x4;
typedef __attribute__((ext_vector_type(16))) float f32x16;

// ---------------- kernel 1a: coeffs -> swizzled bf16 table ----------------
__global__ __launch_bounds__(256)
void kan_prep_coeffs(const float* __restrict__ coeffs, ushort* __restrict__ cws) {
    int n = blockIdx.x * 256 + threadIdx.x;      // 40960 = 64*128*5 exactly
    int i = n / 640;
    int rem = n - i * 640;
    int o = rem / 5;
    int d = rem - o * 5;
    if (d == 0) return;                           // degree 0 -> bias kernel
    int kp = (d - 1) * 64 + i;                    // k' in [0,256)
    int byte = (o * 512 + kp * 2) ^ ((o & 7) << 4);
    __hip_bfloat16 h = __float2bfloat16(coeffs[n]);
    cws[byte >> 1] = *reinterpret_cast<ushort*>(&h);
}

// ---------------- kernel 1b: bias[o] = sum_i coeffs[i][o][0] ----------------
__global__ __launch_bounds__(128)
void kan_prep_bias(const float* __restrict__ coeffs, float* __restrict__ bias) {
    int o = threadIdx.x;
    float s = 0.f;
    #pragma unroll
    for (int i = 0; i < 64; ++i) s += coeffs[i * 640 + o * 5];
    bias[o] = s;
}

// ---------------- main MFMA kernel ----------------
__device__ __forceinline__ float fast_tanh(float v) {
    float e = exp2f(v * 2.885390082f);
    float r = __builtin_amdgcn_rcpf(e + 1.0f);
    return fmaf(-2.0f, r, 1.0f);
}

__device__ __forceinline__ short8 pack8(const float* p) {
    union { short8 v; uint u[4]; } r;
    #pragma unroll
    for (int q = 0; q < 4; ++q) {
        __hip_bfloat162 h = __float22bfloat162_rn(make_float2(p[2*q], p[2*q+1]));
        r.u[q] = *reinterpret_cast<uint*>(&h);
    }
    return r.v;
}

// tanh + Jacobi(1,1) + bf16 pack for 8 x-values -> 4 B-fragments (d=1..4)
__device__ __forceinline__ void make_frags(const float xv[8], short8 bf[4]) {
    float p1a[8], p2a[8], p3a[8], p4a[8];
    #pragma unroll
    for (int j = 0; j < 8; ++j) {
        float t  = fast_tanh(xv[j]);
        float p1 = t + t;                                   // P1 = 2x
        float p2 = fmaf(1.875f * t, p1, -0.75f);            // P2
        float p3 = fmaf(1.8666666666666667f * t, p2, -0.8f * p1);
        float p4 = fmaf(1.875f * t, p3, -0.8333333333333333f * p2);
        p1a[j] = p1; p2a[j] = p2; p3a[j] = p3; p4a[j] = p4;
    }
    bf[0] = pack8(p1a); bf[1] = pack8(p2a);
    bf[2] = pack8(p3a); bf[3] = pack8(p4a);
}

__global__ __launch_bounds__(256)
void kan_mfma(const float* __restrict__ x, const ushort* __restrict__ cws,
              const float* __restrict__ bias, float* __restrict__ y) {
    __shared__ __align__(16) ushort clds[32768];   // 64 KB swizzled C2 table

    const int tid  = threadIdx.x;
    const int w    = tid >> 6;        // wave 0..3
    const int l    = tid & 63;
    const int lh   = l >> 5;          // k-half / row-half selector
    const int ls   = l & 31;          // tile column (c) / o-row within tile
    const int b    = blockIdx.y;
    const int sgrp = blockIdx.x;      // 0..127 -> 512 samples per block

    // ---- stage C table: 64 KB = 16 iters x 256 thr x 16 B (linear) ----
    const char* gsrc  = (const char*)cws;
    char*       lbase = (char*)clds;
    #pragma unroll
    for (int q = 0; q < 16; ++q) {
        int off = (q * 256 + tid) * 16;
        __builtin_amdgcn_global_load_lds(
            (const __attribute__((address_space(1))) uint*)(gsrc + off),
            (__attribute__((address_space(3))) uint*)(lbase + off),
            16, 0, 0);
    }
    __syncthreads();

    const float* xb    = x + (size_t)b * II * SS;
    const int    swz   = (ls & 7) << 4;
    const int    wbase = sgrp * 512 + w * 128;   // wave: 128 consecutive s

    #pragma unroll
    for (int stp = 0; stp < 2; ++stp) {
        const int s0 = wbase + stp * 64;   // pair covers s0..s0+63
                                           // tile A: even s, tile B: odd s

        // ---- acc init = bias fragments (L1-hot after first pair) ----
        f32x16 accA[4], accB[4];
        #pragma unroll
        for (int ot = 0; ot < 4; ++ot) {
            #pragma unroll
            for (int q = 0; q < 4; ++q) {
                f32x4 bv = *(const f32x4*)(bias + ot * 32 + q * 8 + 4 * lh);
                #pragma unroll
                for (int r = 0; r < 4; ++r) {
                    accA[ot][q * 4 + r] = bv[r];
                    accB[ot][q * 4 + r] = bv[r];
                }
            }
        }

        // ---- x loads: float2 per (i): lane ls gets s0+2ls (A), +1 (B) ----
        // one instr = 2 rows x 32 lanes x 8 B = 2 x 256 B contiguous
        float2 xv[2][8];   // [pipe][j], ping-pong over ig
        #pragma unroll
        for (int j = 0; j < 8; ++j) {
            const float2* xp = (const float2*)(xb + (size_t)(8 * lh + j) * SS + s0);
            xv[0][j] = xp[ls];
        }

        #pragma unroll
        for (int ig = 0; ig < 4; ++ig) {
            const int cur = ig & 1;
            if (ig < 3) {   // prefetch next i-group's x
                #pragma unroll
                for (int j = 0; j < 8; ++j) {
                    const float2* xp = (const float2*)(xb + (size_t)((ig + 1) * 16 + 8 * lh + j) * SS + s0);
                    xv[cur ^ 1][j] = xp[ls];
                }
            }

            float xa[8], xo[8];
            #pragma unroll
            for (int j = 0; j < 8; ++j) { xa[j] = xv[cur][j].x; xo[j] = xv[cur][j].y; }

            short8 bfA[4], bfB[4];
            make_frags(xa, bfA);   // even s
            make_frags(xo, bfB);   // odd  s

            #pragma unroll
            for (int di = 0; di < 4; ++di) {
                const int kt = di * 4 + ig;               // k-window
                #pragma unroll
                for (int ot = 0; ot < 4; ++ot) {
                    const int o    = ot * 32 + ls;
                    const int boff = (o * 512 + kt * 32 + 16 * lh) ^ swz;
                    short8 a = *(const short8*)(lbase + boff);   // shared by pair
                    accA[ot] = __builtin_amdgcn_mfma_f32_32x32x16_bf16(a, bfA[di], accA[ot], 0, 0, 0);
                    accB[ot] = __builtin_amdgcn_mfma_f32_32x32x16_bf16(a, bfB[di], accB[ot], 0, 0, 0);
                }
            }
        }

        // ---- store: row = ot*32 + rr + 8q + 4*lh (D layout), col ls ----
        // float2 {even,odd} at s0+2ls: per instr each 32-lane half writes
        // 256 B contiguous in one y row.
        #pragma unroll
        for (int ot = 0; ot < 4; ++ot) {
            #pragma unroll
            for (int q = 0; q < 4; ++q) {
                #pragma unroll
                for (int rr = 0; rr < 4; ++rr) {
                    const int reg  = q * 4 + rr;
                    const int orow = ot * 32 + rr + 8 * q + 4 * lh;
                    float2 v;
                    v.x = accA[ot][reg];
                    v.y = accB[ot][reg];
                    *(float2*)(y + (size_t)(b * OO + orow) * SS + s0 + 2 * ls) = v;
                }
            }
        }
    }
}

extern "C" void kernel_launch(void* const* d_in, const int* in_sizes, int n_in,
                              void* d_out, int out_size, void* d_ws, size_t ws_size,
                              hipStream_t stream) {
    const float* x      = (const float*)d_in[0];
    const float* coeffs = (const float*)d_in[1];
    float* y            = (float*)d_out;

    ushort* cws  = (ushort*)d_ws;                        // 64 KB bf16 table
    float*  bias = (float*)((char*)d_ws + 65536);        // 512 B

    kan_prep_coeffs<<<dim3(160), dim3(256), 0, stream>>>(coeffs, cws);
    kan_prep_bias  <<<dim3(1),   dim3(128), 0, stream>>>(coeffs, bias);
    kan_mfma       <<<dim3(128, 4), dim3(256), 0, stream>>>(x, cws, bias, y);
}